// Round 1
// baseline (477.961 us; speedup 1.0000x reference)
//
#include <hip/hip_runtime.h>

// Problem constants
// B=8, G=3, IN=384, OUT=384, H=64, W=64, CG=128, OG=128

// ---------------------------------------------------------------------------
// Kernel 1: NCHW -> (b,g,y,x,c) transpose of input, c contiguous (128 floats)
// ---------------------------------------------------------------------------
__global__ __launch_bounds__(256) void transpose_x_kernel(
    const float* __restrict__ in, float* __restrict__ xT) {
  __shared__ float tile[32][33];
  const int t  = threadIdx.x;
  const int tx = t & 31, ty = t >> 5;      // 32 x 8
  const int bx = blockIdx.x;               // 0..7 : x-tile (2) x c-tile (4)
  const int x0 = (bx & 1) * 32;
  const int c0 = (bx >> 1) * 32;
  const int y  = blockIdx.y;
  const int bg = blockIdx.z;               // b*3+g
  const int b  = bg / 3, g = bg % 3;

  const float* src = in + ((size_t)(b * 384 + g * 128)) * 4096 + (size_t)y * 64;
#pragma unroll
  for (int it = 0; it < 4; ++it) {
    int c = c0 + ty + it * 8;
    tile[ty + it * 8][tx] = src[(size_t)c * 4096 + x0 + tx];  // coalesced in x
  }
  __syncthreads();
  float* dst = xT + (((size_t)bg * 64 + y) * 64) * 128;
#pragma unroll
  for (int it = 0; it < 4; ++it) {
    int x = x0 + ty + it * 8;
    dst[(size_t)x * 128 + c0 + tx] = tile[tx][ty + it * 8];   // coalesced in c
  }
}

// ---------------------------------------------------------------------------
// Kernel 2: w_d (OUT, CG, 3, 3) -> wT [g][k][c][o]  (o contiguous)
// ---------------------------------------------------------------------------
__global__ __launch_bounds__(256) void transpose_w_kernel(
    const float* __restrict__ w_d, float* __restrict__ wT) {
  int idx = blockIdx.x * 256 + threadIdx.x;   // 3*9*128*128 = 442368
  if (idx >= 442368) return;
  int o  = idx & 127;
  int c  = (idx >> 7) & 127;
  int t2 = idx >> 14;
  int k  = t2 % 9;
  int g  = t2 / 9;
  wT[idx] = w_d[((size_t)(g * 128 + o) * 128 + c) * 9 + k];
}

// ---------------------------------------------------------------------------
// Kernel 3: main fused kernel. Block = (b,g,h): 64 positions x 128 out-chans.
// ---------------------------------------------------------------------------
__global__ __launch_bounds__(256) void fa_main_kernel(
    const float* __restrict__ xT, const float* __restrict__ wT,
    const float* __restrict__ wh_pred, const float* __restrict__ w_off,
    const float* __restrict__ b_off, const float* __restrict__ b_d,
    float* __restrict__ out) {
  __shared__ float py_s[9][64];
  __shared__ float px_s[9][64];
  __shared__ float samp[64][132];   // pad 132: 2-way-max bank aliasing (free)

  const int t = threadIdx.x;
  const int h = blockIdx.x;
  const int g = blockIdx.y;
  const int b = blockIdx.z;

  // --- offsets: off = w_off @ wh + b_off, then add base grid + tap ---------
  for (int idx = t; idx < 576; idx += 256) {
    int k = idx >> 6, pos = idx & 63;
    float wh0 = wh_pred[(((size_t)b * 6 + g * 2 + 0) * 64 + h) * 64 + pos];
    float wh1 = wh_pred[(((size_t)b * 6 + g * 2 + 1) * 64 + h) * 64 + pos];
    int oy_i = g * 18 + k * 2;
    int ox_i = oy_i + 1;
    float oy = fmaf(w_off[oy_i * 2], wh0, fmaf(w_off[oy_i * 2 + 1], wh1, b_off[oy_i]));
    float ox = fmaf(w_off[ox_i * 2], wh0, fmaf(w_off[ox_i * 2 + 1], wh1, b_off[ox_i]));
    py_s[k][pos] = oy + (float)(h + k / 3 - 1);
    px_s[k][pos] = ox + (float)(pos + k % 3 - 1);
  }
  __syncthreads();

  const int pg = t >> 5;   // 0..7  : position group (8 pos each)
  const int og = t & 31;   // 0..31 : out-channel group (4 chans each)

  float acc[8][4];
#pragma unroll
  for (int j = 0; j < 4; ++j) {
    float bias = b_d[g * 128 + og * 4 + j];
#pragma unroll
    for (int i = 0; i < 8; ++i) acc[i][j] = bias;
  }

  const float* xbase = xT + (size_t)(b * 3 + g) * 4096 * 128;
  const int spos = t >> 2;  // staging: 64 pos x 4 c-quarters
  const int scq  = t & 3;

  for (int k = 0; k < 9; ++k) {
    // --- stage bilinear samples for tap k: samp[pos][c] ---------------------
    {
      float py = py_s[k][spos], px = px_s[k][spos];
      float fy = floorf(py), fx = floorf(px);
      int y0 = (int)fy, x0 = (int)fx;
      float wy = py - fy, wx = px - fx;
      int y1 = y0 + 1, x1 = x0 + 1;
      float m_y0 = (y0 >= 0 && y0 < 64) ? 1.f : 0.f;
      float m_y1 = (y1 >= 0 && y1 < 64) ? 1.f : 0.f;
      float m_x0 = (x0 >= 0 && x0 < 64) ? 1.f : 0.f;
      float m_x1 = (x1 >= 0 && x1 < 64) ? 1.f : 0.f;
      float w00 = (1.f - wy) * (1.f - wx) * m_y0 * m_x0;
      float w01 = (1.f - wy) * wx * m_y0 * m_x1;
      float w10 = wy * (1.f - wx) * m_y1 * m_x0;
      float w11 = wy * wx * m_y1 * m_x1;
      int yc0 = min(max(y0, 0), 63), yc1 = min(max(y1, 0), 63);
      int xc0 = min(max(x0, 0), 63), xc1 = min(max(x1, 0), 63);
      const float* p00 = xbase + ((size_t)yc0 * 64 + xc0) * 128;
      const float* p01 = xbase + ((size_t)yc0 * 64 + xc1) * 128;
      const float* p10 = xbase + ((size_t)yc1 * 64 + xc0) * 128;
      const float* p11 = xbase + ((size_t)yc1 * 64 + xc1) * 128;
#pragma unroll
      for (int j = 0; j < 8; ++j) {
        int c = scq * 4 + j * 16;  // 4 lanes cover 64B contiguously
        float4 a00 = *(const float4*)(p00 + c);
        float4 a01 = *(const float4*)(p01 + c);
        float4 a10 = *(const float4*)(p10 + c);
        float4 a11 = *(const float4*)(p11 + c);
        float4 v;
        v.x = fmaf(a00.x, w00, fmaf(a01.x, w01, fmaf(a10.x, w10, a11.x * w11)));
        v.y = fmaf(a00.y, w00, fmaf(a01.y, w01, fmaf(a10.y, w10, a11.y * w11)));
        v.z = fmaf(a00.z, w00, fmaf(a01.z, w01, fmaf(a10.z, w10, a11.z * w11)));
        v.w = fmaf(a00.w, w00, fmaf(a01.w, w01, fmaf(a10.w, w10, a11.w * w11)));
        *(float4*)&samp[spos][c] = v;
      }
    }
    __syncthreads();

    // --- GEMM: acc[pos][o] += samp[pos][c] * wT[g][k][c][o] -----------------
    const float* wk = wT + (size_t)(g * 9 + k) * 128 * 128 + og * 4;
#pragma unroll 2
    for (int c = 0; c < 128; c += 4) {
      float4 w0 = *(const float4*)(wk + (size_t)(c + 0) * 128);
      float4 w1 = *(const float4*)(wk + (size_t)(c + 1) * 128);
      float4 w2 = *(const float4*)(wk + (size_t)(c + 2) * 128);
      float4 w3 = *(const float4*)(wk + (size_t)(c + 3) * 128);
#pragma unroll
      for (int i = 0; i < 8; ++i) {
        float4 s = *(const float4*)&samp[pg * 8 + i][c];
        acc[i][0] = fmaf(s.x, w0.x, acc[i][0]);
        acc[i][0] = fmaf(s.y, w1.x, acc[i][0]);
        acc[i][0] = fmaf(s.z, w2.x, acc[i][0]);
        acc[i][0] = fmaf(s.w, w3.x, acc[i][0]);
        acc[i][1] = fmaf(s.x, w0.y, acc[i][1]);
        acc[i][1] = fmaf(s.y, w1.y, acc[i][1]);
        acc[i][1] = fmaf(s.z, w2.y, acc[i][1]);
        acc[i][1] = fmaf(s.w, w3.y, acc[i][1]);
        acc[i][2] = fmaf(s.x, w0.z, acc[i][2]);
        acc[i][2] = fmaf(s.y, w1.z, acc[i][2]);
        acc[i][2] = fmaf(s.z, w2.z, acc[i][2]);
        acc[i][2] = fmaf(s.w, w3.z, acc[i][2]);
        acc[i][3] = fmaf(s.x, w0.w, acc[i][3]);
        acc[i][3] = fmaf(s.y, w1.w, acc[i][3]);
        acc[i][3] = fmaf(s.z, w2.w, acc[i][3]);
        acc[i][3] = fmaf(s.w, w3.w, acc[i][3]);
      }
    }
    __syncthreads();
  }

  // --- store: out (B, 384, 64, 64) ------------------------------------------
#pragma unroll
  for (int i = 0; i < 8; ++i) {
    int p = pg * 8 + i;
#pragma unroll
    for (int j = 0; j < 4; ++j) {
      out[(((size_t)b * 384 + g * 128 + og * 4 + j) * 64 + h) * 64 + p] = acc[i][j];
    }
  }
}

extern "C" void kernel_launch(void* const* d_in, const int* in_sizes, int n_in,
                              void* d_out, int out_size, void* d_ws, size_t ws_size,
                              hipStream_t stream) {
  const float* input   = (const float*)d_in[0];
  const float* wh_pred = (const float*)d_in[1];
  const float* w_off   = (const float*)d_in[2];
  const float* b_off   = (const float*)d_in[3];
  const float* w_d     = (const float*)d_in[4];
  const float* b_d     = (const float*)d_in[5];
  float* out = (float*)d_out;

  float* xT = (float*)d_ws;                       // 8*3*64*64*128 floats = 50.3 MB
  float* wT = xT + (size_t)8 * 3 * 64 * 64 * 128; // 3*9*128*128 floats = 1.77 MB

  transpose_x_kernel<<<dim3(8, 64, 24), 256, 0, stream>>>(input, xT);
  transpose_w_kernel<<<dim3(1728), 256, 0, stream>>>(w_d, wT);
  fa_main_kernel<<<dim3(64, 3, 8), 256, 0, stream>>>(
      xT, wT, wh_pred, w_off, b_off, b_d, out);
}

// Round 2
// 103.980 us; speedup vs baseline: 4.5967x; 4.5967x over previous
//
#include <hip/hip_runtime.h>

// B=8, G=3, IN=384, OUT=384, H=64, W=64, CG=128, OG=128
// Strategy: fp32 bilinear sampling -> bf16 LDS tiles -> mfma_f32_16x16x32_bf16
//   A = weights (M=out channels), B = samples (N=positions) so C col=lane&15
//   maps to the contiguous W dimension of the output (coalesced stores).

typedef __attribute__((ext_vector_type(8))) short short8;
typedef __attribute__((ext_vector_type(4))) float floatx4;
typedef __attribute__((ext_vector_type(4))) unsigned int uintx4;

__device__ __forceinline__ float bf_lo(unsigned int d) {
  return __uint_as_float(d << 16);
}
__device__ __forceinline__ float bf_hi(unsigned int d) {
  return __uint_as_float(d & 0xffff0000u);
}
__device__ __forceinline__ unsigned int pack_bf16(float lo, float hi) {
  unsigned int ul = (__float_as_uint(lo) + 0x8000u) >> 16;
  unsigned int uh = (__float_as_uint(hi) + 0x8000u) & 0xffff0000u;
  return ul | uh;
}

// ---------------------------------------------------------------------------
// Kernel 1: NCHW fp32 -> (b,g,y,x,c) bf16, c contiguous (128)
// ---------------------------------------------------------------------------
__global__ __launch_bounds__(256) void transpose_x_kernel(
    const float* __restrict__ in, ushort* __restrict__ xT) {
  __shared__ float tile[32][33];
  const int t  = threadIdx.x;
  const int tx = t & 31, ty = t >> 5;      // 32 x 8
  const int bx = blockIdx.x;               // x-tile (2) x c-tile (4)
  const int x0 = (bx & 1) * 32;
  const int c0 = (bx >> 1) * 32;
  const int y  = blockIdx.y;
  const int bg = blockIdx.z;
  const int b  = bg / 3, g = bg % 3;

  const float* src = in + ((size_t)(b * 384 + g * 128)) * 4096 + (size_t)y * 64;
#pragma unroll
  for (int it = 0; it < 4; ++it) {
    int c = c0 + ty + it * 8;
    tile[ty + it * 8][tx] = src[(size_t)c * 4096 + x0 + tx];
  }
  __syncthreads();
  ushort* dst = xT + (((size_t)bg * 64 + y) * 64) * 128;
#pragma unroll
  for (int it = 0; it < 4; ++it) {
    int x = x0 + ty + it * 8;
    float v = tile[tx][ty + it * 8];
    dst[(size_t)x * 128 + c0 + tx] =
        (ushort)((__float_as_uint(v) + 0x8000u) >> 16);
  }
}

// ---------------------------------------------------------------------------
// Kernel 2: w_d (OUT, CG, 3, 3) fp32 -> bf16 A-fragment order:
//   wB[(((g*9+k)*4+s)*8+f)*64+l][j] = w[g][o=f*16+(l&15)][c=s*32+(l>>4)*8+j]
// ---------------------------------------------------------------------------
__global__ __launch_bounds__(256) void swizzle_w_kernel(
    const float* __restrict__ w_d, ushort* __restrict__ wB) {
  int idx = blockIdx.x * 256 + threadIdx.x;  // 442368 total
  if (idx >= 442368) return;
  int j  = idx & 7;
  int l  = (idx >> 3) & 63;
  int f  = (idx >> 9) & 7;
  int s  = (idx >> 12) & 3;
  int t2 = idx >> 14;            // g*9 + k
  int k  = t2 % 9;
  int g  = t2 / 9;
  int o  = f * 16 + (l & 15);
  int c  = s * 32 + (l >> 4) * 8 + j;
  float v = w_d[((size_t)(g * 128 + o) * 128 + c) * 9 + k];
  wB[idx] = (ushort)((__float_as_uint(v) + 0x8000u) >> 16);
}

// ---------------------------------------------------------------------------
// Kernel 3: main fused kernel. Block = (h,g,b): 64 pos x 128 out, 4 waves.
// Wave wv owns out rows [wv*32, wv*32+32) x all 64 pos.
// ---------------------------------------------------------------------------
__global__ __launch_bounds__(256) void fa_main_mfma(
    const ushort* __restrict__ xT, const ushort* __restrict__ wB,
    const float* __restrict__ wh_pred, const float* __restrict__ w_off,
    const float* __restrict__ b_off, const float* __restrict__ b_d,
    float* __restrict__ out) {
  __shared__ float py_s[9][64];
  __shared__ float px_s[9][64];
  __shared__ ushort samp[2][64][136];  // 136-pad: 272B stride = 4-bank rotate

  const int t = threadIdx.x;
  const int h = blockIdx.x;
  const int g = blockIdx.y;
  const int b = blockIdx.z;

  // --- offsets: off = w_off @ wh + b_off + base grid + tap -----------------
  for (int idx = t; idx < 576; idx += 256) {
    int k = idx >> 6, pos = idx & 63;
    float wh0 = wh_pred[(((size_t)b * 6 + g * 2 + 0) * 64 + h) * 64 + pos];
    float wh1 = wh_pred[(((size_t)b * 6 + g * 2 + 1) * 64 + h) * 64 + pos];
    int oy_i = g * 18 + k * 2;
    int ox_i = oy_i + 1;
    float oy = fmaf(w_off[oy_i * 2], wh0, fmaf(w_off[oy_i * 2 + 1], wh1, b_off[oy_i]));
    float ox = fmaf(w_off[ox_i * 2], wh0, fmaf(w_off[ox_i * 2 + 1], wh1, b_off[ox_i]));
    py_s[k][pos] = oy + (float)(h + k / 3 - 1);
    px_s[k][pos] = ox + (float)(pos + k % 3 - 1);
  }
  __syncthreads();

  const int wv  = t >> 6;   // wave 0..3
  const int l   = t & 63;
  const int l15 = l & 15;
  const int lhi = l >> 4;   // 0..3

  // accumulators: acc[ia][jb]; ia = out-frag (2), jb = pos-frag (4)
  floatx4 acc[2][4];
#pragma unroll
  for (int ia = 0; ia < 2; ++ia) {
#pragma unroll
    for (int r = 0; r < 4; ++r) {
      float bias = b_d[g * 128 + wv * 32 + ia * 16 + lhi * 4 + r];
#pragma unroll
      for (int jb = 0; jb < 4; ++jb) acc[ia][jb][r] = bias;
    }
  }

  const int spos = t >> 2;  // staging: 64 pos x 4 c-quarters
  const int scq  = t & 3;
  const ushort* xb = xT + (size_t)(b * 3 + g) * 4096 * 128;
  const ushort* wg = wB + (size_t)g * 9 * 16384;

  for (int k = 0; k < 9; ++k) {
    ushort(*sb)[136] = samp[k & 1];

    // --- stage bilinear samples (fp32 blend -> packed bf16) ----------------
    {
      float py = py_s[k][spos], px = px_s[k][spos];
      float fy = floorf(py), fx = floorf(px);
      int y0 = (int)fy, x0 = (int)fx;
      float wy = py - fy, wx = px - fx;
      int y1 = y0 + 1, x1 = x0 + 1;
      float m_y0 = ((unsigned)y0 < 64u) ? 1.f : 0.f;
      float m_y1 = ((unsigned)y1 < 64u) ? 1.f : 0.f;
      float m_x0 = ((unsigned)x0 < 64u) ? 1.f : 0.f;
      float m_x1 = ((unsigned)x1 < 64u) ? 1.f : 0.f;
      float w00 = (1.f - wy) * (1.f - wx) * m_y0 * m_x0;
      float w01 = (1.f - wy) * wx * m_y0 * m_x1;
      float w10 = wy * (1.f - wx) * m_y1 * m_x0;
      float w11 = wy * wx * m_y1 * m_x1;
      int yc0 = min(max(y0, 0), 63), yc1 = min(max(y1, 0), 63);
      int xc0 = min(max(x0, 0), 63), xc1 = min(max(x1, 0), 63);
      const ushort* p00 = xb + ((size_t)(yc0 * 64 + xc0)) * 128;
      const ushort* p01 = xb + ((size_t)(yc0 * 64 + xc1)) * 128;
      const ushort* p10 = xb + ((size_t)(yc1 * 64 + xc0)) * 128;
      const ushort* p11 = xb + ((size_t)(yc1 * 64 + xc1)) * 128;
#pragma unroll
      for (int j = 0; j < 4; ++j) {
        int c = scq * 8 + j * 32;
        uintx4 a00 = *(const uintx4*)(p00 + c);
        uintx4 a01 = *(const uintx4*)(p01 + c);
        uintx4 a10 = *(const uintx4*)(p10 + c);
        uintx4 a11 = *(const uintx4*)(p11 + c);
        uintx4 pk;
#pragma unroll
        for (int d = 0; d < 4; ++d) {
          float lo = fmaf(bf_lo(a00[d]), w00, fmaf(bf_lo(a01[d]), w01,
                     fmaf(bf_lo(a10[d]), w10, bf_lo(a11[d]) * w11)));
          float hi = fmaf(bf_hi(a00[d]), w00, fmaf(bf_hi(a01[d]), w01,
                     fmaf(bf_hi(a10[d]), w10, bf_hi(a11[d]) * w11)));
          pk[d] = pack_bf16(lo, hi);
        }
        *(uintx4*)&sb[spos][c] = pk;
      }
    }
    __syncthreads();  // dbuf parity: one barrier per tap is sufficient

    // --- MFMA: acc += W_frag x S_frag over K=128 (4 ksteps) ----------------
    const ushort* wk = wg + (size_t)k * 16384;
#pragma unroll
    for (int s = 0; s < 4; ++s) {
      short8 a0 = *(const short8*)(wk + ((s * 8 + wv * 2 + 0) * 64 + l) * 8);
      short8 a1 = *(const short8*)(wk + ((s * 8 + wv * 2 + 1) * 64 + l) * 8);
      const int cb = s * 32 + lhi * 8;
#pragma unroll
      for (int jb = 0; jb < 4; ++jb) {
        short8 bf = *(const short8*)&sb[jb * 16 + l15][cb];
        acc[0][jb] = __builtin_amdgcn_mfma_f32_16x16x32_bf16(a0, bf, acc[0][jb], 0, 0, 0);
        acc[1][jb] = __builtin_amdgcn_mfma_f32_16x16x32_bf16(a1, bf, acc[1][jb], 0, 0, 0);
      }
    }
  }

  // --- store: out (B, 384, H, W); C col(lane&15) = pos = contiguous W -------
#pragma unroll
  for (int ia = 0; ia < 2; ++ia) {
#pragma unroll
    for (int jb = 0; jb < 4; ++jb) {
#pragma unroll
      for (int r = 0; r < 4; ++r) {
        int o = wv * 32 + ia * 16 + lhi * 4 + r;
        int pos = jb * 16 + l15;
        out[(((size_t)(b * 384 + g * 128 + o)) * 64 + h) * 64 + pos] = acc[ia][jb][r];
      }
    }
  }
}

extern "C" void kernel_launch(void* const* d_in, const int* in_sizes, int n_in,
                              void* d_out, int out_size, void* d_ws, size_t ws_size,
                              hipStream_t stream) {
  const float* input   = (const float*)d_in[0];
  const float* wh_pred = (const float*)d_in[1];
  const float* w_off   = (const float*)d_in[2];
  const float* b_off   = (const float*)d_in[3];
  const float* w_d     = (const float*)d_in[4];
  const float* b_d     = (const float*)d_in[5];
  float* out = (float*)d_out;

  ushort* xT = (ushort*)d_ws;                       // 8*3*64*64*128 bf16 = 25.2 MB
  ushort* wB = xT + (size_t)8 * 3 * 64 * 64 * 128;  // 442368 bf16 = 0.88 MB

  transpose_x_kernel<<<dim3(8, 64, 24), 256, 0, stream>>>(input, xT);
  swizzle_w_kernel<<<dim3(1728), 256, 0, stream>>>(w_d, wB);
  fa_main_mfma<<<dim3(64, 3, 8), 256, 0, stream>>>(
      xT, wB, wh_pred, w_off, b_off, b_d, out);
}

// Round 4
// 88.378 us; speedup vs baseline: 5.4081x; 1.1765x over previous
//
#include <hip/hip_runtime.h>

// B=8, G=3, IN=384, OUT=384, H=64, W=64, CG=128, OG=128
// fp32 bilinear sampling -> bf16 LDS tile -> mfma_f32_16x16x32_bf16.
// R4: revert to R2 compute structure (R3's register pipeline miscompiled);
//     single-buffer LDS (22 KB -> 7 blocks/CU, TLP latency hiding) +
//     XCD-aware swizzle (b = bid&7 pins each batch image to one XCD L2).

typedef __attribute__((ext_vector_type(8))) short short8;
typedef __attribute__((ext_vector_type(4))) float floatx4;
typedef __attribute__((ext_vector_type(4))) unsigned int uintx4;

__device__ __forceinline__ float bf_lo(unsigned int d) {
  return __uint_as_float(d << 16);
}
__device__ __forceinline__ float bf_hi(unsigned int d) {
  return __uint_as_float(d & 0xffff0000u);
}
__device__ __forceinline__ unsigned int pack_bf16(float lo, float hi) {
  unsigned int ul = (__float_as_uint(lo) + 0x8000u) >> 16;
  unsigned int uh = (__float_as_uint(hi) + 0x8000u) & 0xffff0000u;
  return ul | uh;
}

// ---------------------------------------------------------------------------
// Kernel 1: NCHW fp32 -> (b,g,y,x,c) bf16, c contiguous (128)
// ---------------------------------------------------------------------------
__global__ __launch_bounds__(256) void transpose_x_kernel(
    const float* __restrict__ in, ushort* __restrict__ xT) {
  __shared__ float tile[32][33];
  const int t  = threadIdx.x;
  const int tx = t & 31, ty = t >> 5;      // 32 x 8
  const int bx = blockIdx.x;               // x-tile (2) x c-tile (4)
  const int x0 = (bx & 1) * 32;
  const int c0 = (bx >> 1) * 32;
  const int y  = blockIdx.y;
  const int bg = blockIdx.z;
  const int b  = bg / 3, g = bg % 3;

  const float* src = in + ((size_t)(b * 384 + g * 128)) * 4096 + (size_t)y * 64;
#pragma unroll
  for (int it = 0; it < 4; ++it) {
    int c = c0 + ty + it * 8;
    tile[ty + it * 8][tx] = src[(size_t)c * 4096 + x0 + tx];
  }
  __syncthreads();
  ushort* dst = xT + (((size_t)bg * 64 + y) * 64) * 128;
#pragma unroll
  for (int it = 0; it < 4; ++it) {
    int x = x0 + ty + it * 8;
    float v = tile[tx][ty + it * 8];
    dst[(size_t)x * 128 + c0 + tx] =
        (ushort)((__float_as_uint(v) + 0x8000u) >> 16);
  }
}

// ---------------------------------------------------------------------------
// Kernel 2: w_d (OUT, CG, 3, 3) fp32 -> bf16 A-fragment order:
//   wB[(((g*9+k)*4+s)*8+f)*64+l][j] = w[g][o=f*16+(l&15)][c=s*32+(l>>4)*8+j]
// ---------------------------------------------------------------------------
__global__ __launch_bounds__(256) void swizzle_w_kernel(
    const float* __restrict__ w_d, ushort* __restrict__ wB) {
  int idx = blockIdx.x * 256 + threadIdx.x;  // 442368 total
  if (idx >= 442368) return;
  int j  = idx & 7;
  int l  = (idx >> 3) & 63;
  int f  = (idx >> 9) & 7;
  int s  = (idx >> 12) & 3;
  int t2 = idx >> 14;            // g*9 + k
  int k  = t2 % 9;
  int g  = t2 / 9;
  int o  = f * 16 + (l & 15);
  int c  = s * 32 + (l >> 4) * 8 + j;
  float v = w_d[((size_t)(g * 128 + o) * 128 + c) * 9 + k];
  wB[idx] = (ushort)((__float_as_uint(v) + 0x8000u) >> 16);
}

// ---------------------------------------------------------------------------
// Kernel 3: main fused kernel. 1536 blocks, XCD-swizzled: b = bid&7.
// Block = (b,g,h): 64 pos x 128 out, 4 waves. Single LDS buffer, 2 barriers
// per tap; occupancy (7 blocks/CU by LDS) provides the latency hiding.
// ---------------------------------------------------------------------------
__global__ __launch_bounds__(256) void fa_main_mfma(
    const ushort* __restrict__ xT, const ushort* __restrict__ wB,
    const float* __restrict__ wh_pred, const float* __restrict__ w_off,
    const float* __restrict__ b_off, const float* __restrict__ b_d,
    float* __restrict__ out) {
  __shared__ float py_s[9][64];
  __shared__ float px_s[9][64];
  __shared__ ushort samp[64][136];  // 272B row stride; 22016 B total LDS

  const int t   = threadIdx.x;
  const int bid = blockIdx.x;
  const int b   = bid & 7;         // XCD-pinned batch image
  const int rem = bid >> 3;
  const int g   = rem >> 6;
  const int h   = rem & 63;

  // --- offsets: off = w_off @ wh + b_off + base grid + tap -----------------
  for (int idx = t; idx < 576; idx += 256) {
    int k = idx >> 6, pos = idx & 63;
    float wh0 = wh_pred[(((size_t)b * 6 + g * 2 + 0) * 64 + h) * 64 + pos];
    float wh1 = wh_pred[(((size_t)b * 6 + g * 2 + 1) * 64 + h) * 64 + pos];
    int oy_i = g * 18 + k * 2;
    int ox_i = oy_i + 1;
    float oy = fmaf(w_off[oy_i * 2], wh0, fmaf(w_off[oy_i * 2 + 1], wh1, b_off[oy_i]));
    float ox = fmaf(w_off[ox_i * 2], wh0, fmaf(w_off[ox_i * 2 + 1], wh1, b_off[ox_i]));
    py_s[k][pos] = oy + (float)(h + k / 3 - 1);
    px_s[k][pos] = ox + (float)(pos + k % 3 - 1);
  }
  __syncthreads();

  const int wv  = t >> 6;   // wave 0..3
  const int l   = t & 63;
  const int l15 = l & 15;
  const int lhi = l >> 4;   // 0..3

  floatx4 acc[2][4];
#pragma unroll
  for (int ia = 0; ia < 2; ++ia) {
#pragma unroll
    for (int r = 0; r < 4; ++r) {
      float bias = b_d[g * 128 + wv * 32 + ia * 16 + lhi * 4 + r];
#pragma unroll
      for (int jb = 0; jb < 4; ++jb) acc[ia][jb][r] = bias;
    }
  }

  const int spos = t >> 2;  // staging: 64 pos x 4 c-quarters
  const int scq  = t & 3;
  const ushort* xb = xT + (size_t)(b * 3 + g) * 4096 * 128;
  const ushort* wg = wB + (size_t)g * 9 * 16384;

  for (int k = 0; k < 9; ++k) {
    // --- stage bilinear samples (fp32 blend -> packed bf16) ----------------
    {
      float py = py_s[k][spos], px = px_s[k][spos];
      float fy = floorf(py), fx = floorf(px);
      int y0 = (int)fy, x0 = (int)fx;
      float wy = py - fy, wx = px - fx;
      int y1 = y0 + 1, x1 = x0 + 1;
      float m_y0 = ((unsigned)y0 < 64u) ? 1.f : 0.f;
      float m_y1 = ((unsigned)y1 < 64u) ? 1.f : 0.f;
      float m_x0 = ((unsigned)x0 < 64u) ? 1.f : 0.f;
      float m_x1 = ((unsigned)x1 < 64u) ? 1.f : 0.f;
      float w00 = (1.f - wy) * (1.f - wx) * m_y0 * m_x0;
      float w01 = (1.f - wy) * wx * m_y0 * m_x1;
      float w10 = wy * (1.f - wx) * m_y1 * m_x0;
      float w11 = wy * wx * m_y1 * m_x1;
      int yc0 = min(max(y0, 0), 63), yc1 = min(max(y1, 0), 63);
      int xc0 = min(max(x0, 0), 63), xc1 = min(max(x1, 0), 63);
      const ushort* p00 = xb + ((size_t)(yc0 * 64 + xc0)) * 128;
      const ushort* p01 = xb + ((size_t)(yc0 * 64 + xc1)) * 128;
      const ushort* p10 = xb + ((size_t)(yc1 * 64 + xc0)) * 128;
      const ushort* p11 = xb + ((size_t)(yc1 * 64 + xc1)) * 128;
#pragma unroll
      for (int j = 0; j < 4; ++j) {
        int c = scq * 8 + j * 32;
        uintx4 a00 = *(const uintx4*)(p00 + c);
        uintx4 a01 = *(const uintx4*)(p01 + c);
        uintx4 a10 = *(const uintx4*)(p10 + c);
        uintx4 a11 = *(const uintx4*)(p11 + c);
        uintx4 pk;
#pragma unroll
        for (int d = 0; d < 4; ++d) {
          float lo = fmaf(bf_lo(a00[d]), w00, fmaf(bf_lo(a01[d]), w01,
                     fmaf(bf_lo(a10[d]), w10, bf_lo(a11[d]) * w11)));
          float hi = fmaf(bf_hi(a00[d]), w00, fmaf(bf_hi(a01[d]), w01,
                     fmaf(bf_hi(a10[d]), w10, bf_hi(a11[d]) * w11)));
          pk[d] = pack_bf16(lo, hi);
        }
        *(uintx4*)&samp[spos][c] = pk;
      }
    }
    __syncthreads();

    // --- MFMA: acc += W_frag x S_frag over K=128 (4 ksteps) ----------------
    const ushort* wk = wg + (size_t)k * 16384;
#pragma unroll
    for (int s = 0; s < 4; ++s) {
      short8 a0 = *(const short8*)(wk + ((s * 8 + wv * 2 + 0) * 64 + l) * 8);
      short8 a1 = *(const short8*)(wk + ((s * 8 + wv * 2 + 1) * 64 + l) * 8);
      const int cb = s * 32 + lhi * 8;
#pragma unroll
      for (int jb = 0; jb < 4; ++jb) {
        short8 bf = *(const short8*)&samp[jb * 16 + l15][cb];
        acc[0][jb] = __builtin_amdgcn_mfma_f32_16x16x32_bf16(a0, bf, acc[0][jb], 0, 0, 0);
        acc[1][jb] = __builtin_amdgcn_mfma_f32_16x16x32_bf16(a1, bf, acc[1][jb], 0, 0, 0);
      }
    }
    __syncthreads();  // samp reads done before next tap's writes
  }

  // --- store: out (B, 384, H, W); C col(lane&15) = pos = contiguous W -------
#pragma unroll
  for (int ia = 0; ia < 2; ++ia) {
#pragma unroll
    for (int jb = 0; jb < 4; ++jb) {
#pragma unroll
      for (int r = 0; r < 4; ++r) {
        int o = wv * 32 + ia * 16 + lhi * 4 + r;
        int pos = jb * 16 + l15;
        out[(((size_t)(b * 384 + g * 128 + o)) * 64 + h) * 64 + pos] = acc[ia][jb][r];
      }
    }
  }
}

extern "C" void kernel_launch(void* const* d_in, const int* in_sizes, int n_in,
                              void* d_out, int out_size, void* d_ws, size_t ws_size,
                              hipStream_t stream) {
  const float* input   = (const float*)d_in[0];
  const float* wh_pred = (const float*)d_in[1];
  const float* w_off   = (const float*)d_in[2];
  const float* b_off   = (const float*)d_in[3];
  const float* w_d     = (const float*)d_in[4];
  const float* b_d     = (const float*)d_in[5];
  float* out = (float*)d_out;

  ushort* xT = (ushort*)d_ws;                       // 8*3*64*64*128 bf16 = 25.2 MB
  ushort* wB = xT + (size_t)8 * 3 * 64 * 64 * 128;  // 442368 bf16 = 0.88 MB

  transpose_x_kernel<<<dim3(8, 64, 24), 256, 0, stream>>>(input, xT);
  swizzle_w_kernel<<<dim3(1728), 256, 0, stream>>>(w_d, wB);
  fa_main_mfma<<<dim3(1536), 256, 0, stream>>>(
      xT, wB, wh_pred, w_off, b_off, b_d, out);
}

// Round 5
// 87.825 us; speedup vs baseline: 5.4422x; 1.0063x over previous
//
#include <hip/hip_runtime.h>

// B=8, G=3, IN=384, OUT=384, H=64, W=64, CG=128, OG=128
// fp32 bilinear sampling -> bf16 LDS tile -> mfma_f32_16x16x32_bf16.
// R5: hoist per-(tap,pos) weight/offset setup into LDS (kills 4x scq
//     redundancy + per-tap recompute); fixed corner offsets (+128/+8192/
//     +8320 shorts) via clamped base + guard margins around xT;
//     v_cvt_pk_bf16_f32 for the bf16 pack. XCD swizzle kept (b = bid&7).

typedef __attribute__((ext_vector_type(8))) short short8;
typedef __attribute__((ext_vector_type(4))) float floatx4;
typedef __attribute__((ext_vector_type(4))) unsigned int uintx4;

#define SLAB 524288            // 64*64*128 shorts per (b,g)
#define XT_GUARD 8704          // head guard, shorts (min 8320 needed)
#define XT_TAIL 512            // tail guard, shorts (min 256 needed)

__device__ __forceinline__ float bf_lo(unsigned int d) {
  return __uint_as_float(d << 16);
}
__device__ __forceinline__ float bf_hi(unsigned int d) {
  return __uint_as_float(d & 0xffff0000u);
}
__device__ __forceinline__ unsigned int cvtpk_bf16(float lo, float hi) {
  unsigned int r;
  asm("v_cvt_pk_bf16_f32 %0, %1, %2" : "=v"(r) : "v"(lo), "v"(hi));
  return r;
}

// ---------------------------------------------------------------------------
// Kernel 1: NCHW fp32 -> (b,g,y,x,c) bf16, c contiguous (128)
// ---------------------------------------------------------------------------
__global__ __launch_bounds__(256) void transpose_x_kernel(
    const float* __restrict__ in, ushort* __restrict__ xT) {
  __shared__ float tile[32][33];
  const int t  = threadIdx.x;
  const int tx = t & 31, ty = t >> 5;      // 32 x 8
  const int bx = blockIdx.x;               // x-tile (2) x c-tile (4)
  const int x0 = (bx & 1) * 32;
  const int c0 = (bx >> 1) * 32;
  const int y  = blockIdx.y;
  const int bg = blockIdx.z;
  const int b  = bg / 3, g = bg % 3;

  const float* src = in + ((size_t)(b * 384 + g * 128)) * 4096 + (size_t)y * 64;
#pragma unroll
  for (int it = 0; it < 4; ++it) {
    int c = c0 + ty + it * 8;
    tile[ty + it * 8][tx] = src[(size_t)c * 4096 + x0 + tx];
  }
  __syncthreads();
  ushort* dst = xT + (((size_t)bg * 64 + y) * 64) * 128;
#pragma unroll
  for (int it = 0; it < 4; ++it) {
    int x = x0 + ty + it * 8;
    float v = tile[tx][ty + it * 8];
    dst[(size_t)x * 128 + c0 + tx] =
        (ushort)((__float_as_uint(v) + 0x8000u) >> 16);
  }
}

// ---------------------------------------------------------------------------
// Kernel 2: w_d (OUT, CG, 3, 3) fp32 -> bf16 A-fragment order:
//   wB[(((g*9+k)*4+s)*8+f)*64+l][j] = w[g][o=f*16+(l&15)][c=s*32+(l>>4)*8+j]
// ---------------------------------------------------------------------------
__global__ __launch_bounds__(256) void swizzle_w_kernel(
    const float* __restrict__ w_d, ushort* __restrict__ wB) {
  int idx = blockIdx.x * 256 + threadIdx.x;  // 442368 total
  if (idx >= 442368) return;
  int j  = idx & 7;
  int l  = (idx >> 3) & 63;
  int f  = (idx >> 9) & 7;
  int s  = (idx >> 12) & 3;
  int t2 = idx >> 14;            // g*9 + k
  int k  = t2 % 9;
  int g  = t2 / 9;
  int o  = f * 16 + (l & 15);
  int c  = s * 32 + (l >> 4) * 8 + j;
  float v = w_d[((size_t)(g * 128 + o) * 128 + c) * 9 + k];
  wB[idx] = (ushort)((__float_as_uint(v) + 0x8000u) >> 16);
}

// ---------------------------------------------------------------------------
// Kernel 3: main fused kernel. 1536 blocks, XCD-swizzled: b = bid&7.
// Block = (b,g,h): 64 pos x 128 out, 4 waves.
// ---------------------------------------------------------------------------
__global__ __launch_bounds__(256) void fa_main_mfma(
    const ushort* __restrict__ xT, const ushort* __restrict__ wB,
    const float* __restrict__ wh_pred, const float* __restrict__ w_off,
    const float* __restrict__ b_off, const float* __restrict__ b_d,
    float* __restrict__ out) {
  __shared__ int    off_s[9][64];
  __shared__ float4 w4_s[9][64];
  __shared__ ushort samp[64][136];  // 272B row stride; 16B-aligned chunks

  const int t   = threadIdx.x;
  const int bid = blockIdx.x;
  const int b   = bid & 7;         // XCD-pinned batch image
  const int rem = bid >> 3;
  const int g   = rem >> 6;
  const int h   = rem & 63;

  // --- prologue: per (tap,pos) bilinear weights + clamped base offset ------
  for (int idx = t; idx < 576; idx += 256) {
    int k = idx >> 6, pos = idx & 63;
    float wh0 = wh_pred[(((size_t)b * 6 + g * 2 + 0) * 64 + h) * 64 + pos];
    float wh1 = wh_pred[(((size_t)b * 6 + g * 2 + 1) * 64 + h) * 64 + pos];
    int oy_i = g * 18 + k * 2;
    int ox_i = oy_i + 1;
    float oy = fmaf(w_off[oy_i * 2], wh0, fmaf(w_off[oy_i * 2 + 1], wh1, b_off[oy_i]));
    float ox = fmaf(w_off[ox_i * 2], wh0, fmaf(w_off[ox_i * 2 + 1], wh1, b_off[ox_i]));
    float py = oy + (float)(h + k / 3 - 1);
    float px = ox + (float)(pos + k % 3 - 1);

    float fy = floorf(py), fx = floorf(px);
    int y0 = (int)fy, x0 = (int)fx;
    float wy = py - fy, wx = px - fx;
    float m_y0 = ((unsigned)y0 < 64u) ? 1.f : 0.f;
    float m_y1 = ((unsigned)(y0 + 1) < 64u) ? 1.f : 0.f;
    float m_x0 = ((unsigned)x0 < 64u) ? 1.f : 0.f;
    float m_x1 = ((unsigned)(x0 + 1) < 64u) ? 1.f : 0.f;
    float4 w4;
    w4.x = (1.f - wy) * (1.f - wx) * m_y0 * m_x0;
    w4.y = (1.f - wy) * wx * m_y0 * m_x1;
    w4.z = wy * (1.f - wx) * m_y1 * m_x0;
    w4.w = wy * wx * m_y1 * m_x1;
    // clamp base so all 4 fixed-offset corners stay within guard margins;
    // masks (from unclamped coords) zero any wrapped/garbage reads.
    int y0c = min(max(y0, -1), 63);
    int x0c = min(max(x0, -1), 63);
    off_s[k][pos] = (y0c * 64 + x0c) * 128;
    w4_s[k][pos]  = w4;
  }
  __syncthreads();

  const int wv  = t >> 6;   // wave 0..3
  const int l   = t & 63;
  const int l15 = l & 15;
  const int lhi = l >> 4;   // 0..3

  floatx4 acc[2][4];
#pragma unroll
  for (int ia = 0; ia < 2; ++ia) {
#pragma unroll
    for (int r = 0; r < 4; ++r) {
      float bias = b_d[g * 128 + wv * 32 + ia * 16 + lhi * 4 + r];
#pragma unroll
      for (int jb = 0; jb < 4; ++jb) acc[ia][jb][r] = bias;
    }
  }

  const int spos = t >> 2;  // staging: 64 pos x 4 c-quarters
  const int scq  = t & 3;
  const ushort* xb = xT + (size_t)(b * 3 + g) * SLAB;
  const ushort* wg = wB + (size_t)g * 9 * 16384;

  for (int k = 0; k < 9; ++k) {
    // --- stage bilinear samples (fp32 blend -> packed bf16) ----------------
    {
      int off   = off_s[k][spos];
      float4 w4 = w4_s[k][spos];
      const ushort* p00 = xb + off + scq * 8;  // corners: +0,+128,+8192,+8320
      const ushort* p10 = p00 + 8192;
#pragma unroll
      for (int j = 0; j < 4; ++j) {
        uintx4 a00 = *(const uintx4*)(p00 + j * 32);
        uintx4 a01 = *(const uintx4*)(p00 + j * 32 + 128);
        uintx4 a10 = *(const uintx4*)(p10 + j * 32);
        uintx4 a11 = *(const uintx4*)(p10 + j * 32 + 128);
        uintx4 pk;
#pragma unroll
        for (int d = 0; d < 4; ++d) {
          float lo = fmaf(bf_lo(a11[d]), w4.w, fmaf(bf_lo(a10[d]), w4.z,
                     fmaf(bf_lo(a01[d]), w4.y, bf_lo(a00[d]) * w4.x)));
          float hi = fmaf(bf_hi(a11[d]), w4.w, fmaf(bf_hi(a10[d]), w4.z,
                     fmaf(bf_hi(a01[d]), w4.y, bf_hi(a00[d]) * w4.x)));
          pk[d] = cvtpk_bf16(lo, hi);
        }
        *(uintx4*)&samp[spos][scq * 8 + j * 32] = pk;
      }
    }
    __syncthreads();

    // --- MFMA: acc += W_frag x S_frag over K=128 (4 ksteps) ----------------
    const ushort* wk = wg + (size_t)k * 16384;
#pragma unroll
    for (int s = 0; s < 4; ++s) {
      short8 a0 = *(const short8*)(wk + ((s * 8 + wv * 2 + 0) * 64 + l) * 8);
      short8 a1 = *(const short8*)(wk + ((s * 8 + wv * 2 + 1) * 64 + l) * 8);
      const int cb = s * 32 + lhi * 8;
#pragma unroll
      for (int jb = 0; jb < 4; ++jb) {
        short8 bf = *(const short8*)&samp[jb * 16 + l15][cb];
        acc[0][jb] = __builtin_amdgcn_mfma_f32_16x16x32_bf16(a0, bf, acc[0][jb], 0, 0, 0);
        acc[1][jb] = __builtin_amdgcn_mfma_f32_16x16x32_bf16(a1, bf, acc[1][jb], 0, 0, 0);
      }
    }
    __syncthreads();  // samp reads done before next tap's writes
  }

  // --- store: out (B, 384, H, W); C col(lane&15) = pos = contiguous W -------
#pragma unroll
  for (int ia = 0; ia < 2; ++ia) {
#pragma unroll
    for (int jb = 0; jb < 4; ++jb) {
#pragma unroll
      for (int r = 0; r < 4; ++r) {
        int o = wv * 32 + ia * 16 + lhi * 4 + r;
        int pos = jb * 16 + l15;
        out[(((size_t)(b * 384 + g * 128 + o)) * 64 + h) * 64 + pos] = acc[ia][jb][r];
      }
    }
  }
}

extern "C" void kernel_launch(void* const* d_in, const int* in_sizes, int n_in,
                              void* d_out, int out_size, void* d_ws, size_t ws_size,
                              hipStream_t stream) {
  const float* input   = (const float*)d_in[0];
  const float* wh_pred = (const float*)d_in[1];
  const float* w_off   = (const float*)d_in[2];
  const float* b_off   = (const float*)d_in[3];
  const float* w_d     = (const float*)d_in[4];
  const float* b_d     = (const float*)d_in[5];
  float* out = (float*)d_out;

  // layout: [head guard][24 slabs of xT][tail guard][wB]
  ushort* xT = (ushort*)d_ws + XT_GUARD;            // 24*SLAB shorts = 25.2 MB
  ushort* wB = xT + (size_t)24 * SLAB + XT_TAIL;    // 442368 bf16 = 0.88 MB

  transpose_x_kernel<<<dim3(8, 64, 24), 256, 0, stream>>>(input, xT);
  swizzle_w_kernel<<<dim3(1728), 256, 0, stream>>>(w_d, wB);
  fa_main_mfma<<<dim3(1536), 256, 0, stream>>>(
      xT, wB, wh_pred, w_off, b_off, b_d, out);
}

// Round 6
// 87.513 us; speedup vs baseline: 5.4616x; 1.0036x over previous
//
#include <hip/hip_runtime.h>

// B=8, G=3, IN=384, OUT=384, H=64, W=64, CG=128, OG=128
// fp32 bilinear sampling -> bf16 LDS tile -> mfma_f32_16x16x32_bf16.
// R6: 32-pos blocks (grid 3072, LDS 13.9 KB -> 8 blocks/CU wave-cap
//     residency, was 5) + XOR-swizzled samp (col ^= (row&7)<<3 shorts)
//     replacing pad -> staging ds_write conflicts (the constant 5.3M) die.
//     Numerically identical to R5. XCD swizzle kept (b = bid&7).

typedef __attribute__((ext_vector_type(8))) short short8;
typedef __attribute__((ext_vector_type(4))) float floatx4;
typedef __attribute__((ext_vector_type(4))) unsigned int uintx4;

#define SLAB 524288            // 64*64*128 shorts per (b,g)
#define XT_GUARD 8704          // head guard, shorts (min 8320 needed)
#define XT_TAIL 512            // tail guard, shorts (min 376 needed)

__device__ __forceinline__ float bf_lo(unsigned int d) {
  return __uint_as_float(d << 16);
}
__device__ __forceinline__ float bf_hi(unsigned int d) {
  return __uint_as_float(d & 0xffff0000u);
}
__device__ __forceinline__ unsigned int cvtpk_bf16(float lo, float hi) {
  unsigned int r;
  asm("v_cvt_pk_bf16_f32 %0, %1, %2" : "=v"(r) : "v"(lo), "v"(hi));
  return r;
}

// ---------------------------------------------------------------------------
// Kernel 1: NCHW fp32 -> (b,g,y,x,c) bf16, c contiguous (128)
// ---------------------------------------------------------------------------
__global__ __launch_bounds__(256) void transpose_x_kernel(
    const float* __restrict__ in, ushort* __restrict__ xT) {
  __shared__ float tile[32][33];
  const int t  = threadIdx.x;
  const int tx = t & 31, ty = t >> 5;      // 32 x 8
  const int bx = blockIdx.x;               // x-tile (2) x c-tile (4)
  const int x0 = (bx & 1) * 32;
  const int c0 = (bx >> 1) * 32;
  const int y  = blockIdx.y;
  const int bg = blockIdx.z;
  const int b  = bg / 3, g = bg % 3;

  const float* src = in + ((size_t)(b * 384 + g * 128)) * 4096 + (size_t)y * 64;
#pragma unroll
  for (int it = 0; it < 4; ++it) {
    int c = c0 + ty + it * 8;
    tile[ty + it * 8][tx] = src[(size_t)c * 4096 + x0 + tx];
  }
  __syncthreads();
  ushort* dst = xT + (((size_t)bg * 64 + y) * 64) * 128;
#pragma unroll
  for (int it = 0; it < 4; ++it) {
    int x = x0 + ty + it * 8;
    float v = tile[tx][ty + it * 8];
    dst[(size_t)x * 128 + c0 + tx] =
        (ushort)((__float_as_uint(v) + 0x8000u) >> 16);
  }
}

// ---------------------------------------------------------------------------
// Kernel 2: w_d (OUT, CG, 3, 3) fp32 -> bf16 A-fragment order:
//   wB[(((g*9+k)*4+s)*8+f)*64+l][j] = w[g][o=f*16+(l&15)][c=s*32+(l>>4)*8+j]
// ---------------------------------------------------------------------------
__global__ __launch_bounds__(256) void swizzle_w_kernel(
    const float* __restrict__ w_d, ushort* __restrict__ wB) {
  int idx = blockIdx.x * 256 + threadIdx.x;  // 442368 total
  if (idx >= 442368) return;
  int j  = idx & 7;
  int l  = (idx >> 3) & 63;
  int f  = (idx >> 9) & 7;
  int s  = (idx >> 12) & 3;
  int t2 = idx >> 14;            // g*9 + k
  int k  = t2 % 9;
  int g  = t2 / 9;
  int o  = f * 16 + (l & 15);
  int c  = s * 32 + (l >> 4) * 8 + j;
  float v = w_d[((size_t)(g * 128 + o) * 128 + c) * 9 + k];
  wB[idx] = (ushort)((__float_as_uint(v) + 0x8000u) >> 16);
}

// ---------------------------------------------------------------------------
// Kernel 3: main fused kernel. 3072 blocks, XCD-swizzled: b = bid&7.
// Block = (b,g,h,ph): 32 positions x 128 out-chans, 4 waves.
// ---------------------------------------------------------------------------
__global__ __launch_bounds__(256) void fa_main_mfma(
    const ushort* __restrict__ xT, const ushort* __restrict__ wB,
    const float* __restrict__ wh_pred, const float* __restrict__ w_off,
    const float* __restrict__ b_off, const float* __restrict__ b_d,
    float* __restrict__ out) {
  __shared__ int    off_s[9][32];
  __shared__ float4 w4_s[9][32];
  __shared__ ushort samp[32][128];  // XOR-swizzled: col ^= (row&7)<<3 shorts

  const int t   = threadIdx.x;
  const int bid = blockIdx.x;
  const int b   = bid & 7;          // XCD-pinned batch image
  const int rem = bid >> 3;         // 0..383 = (g*64 + h)*2 + ph
  const int ph  = rem & 1;
  const int h   = (rem >> 1) & 63;
  const int g   = rem >> 7;
  const int pos0 = ph * 32;

  // --- prologue: per (tap,pos) bilinear weights + clamped base offset ------
  for (int idx = t; idx < 288; idx += 256) {
    int k = idx >> 5, pos = idx & 31;
    int posg = pos0 + pos;
    float wh0 = wh_pred[(((size_t)b * 6 + g * 2 + 0) * 64 + h) * 64 + posg];
    float wh1 = wh_pred[(((size_t)b * 6 + g * 2 + 1) * 64 + h) * 64 + posg];
    int oy_i = g * 18 + k * 2;
    int ox_i = oy_i + 1;
    float oy = fmaf(w_off[oy_i * 2], wh0, fmaf(w_off[oy_i * 2 + 1], wh1, b_off[oy_i]));
    float ox = fmaf(w_off[ox_i * 2], wh0, fmaf(w_off[ox_i * 2 + 1], wh1, b_off[ox_i]));
    float py = oy + (float)(h + k / 3 - 1);
    float px = ox + (float)(posg + k % 3 - 1);

    float fy = floorf(py), fx = floorf(px);
    int y0 = (int)fy, x0 = (int)fx;
    float wy = py - fy, wx = px - fx;
    float m_y0 = ((unsigned)y0 < 64u) ? 1.f : 0.f;
    float m_y1 = ((unsigned)(y0 + 1) < 64u) ? 1.f : 0.f;
    float m_x0 = ((unsigned)x0 < 64u) ? 1.f : 0.f;
    float m_x1 = ((unsigned)(x0 + 1) < 64u) ? 1.f : 0.f;
    float4 w4;
    w4.x = (1.f - wy) * (1.f - wx) * m_y0 * m_x0;
    w4.y = (1.f - wy) * wx * m_y0 * m_x1;
    w4.z = wy * (1.f - wx) * m_y1 * m_x0;
    w4.w = wy * wx * m_y1 * m_x1;
    int y0c = min(max(y0, -1), 63);
    int x0c = min(max(x0, -1), 63);
    off_s[k][pos] = (y0c * 64 + x0c) * 128;
    w4_s[k][pos]  = w4;
  }
  __syncthreads();

  const int wv  = t >> 6;   // wave 0..3
  const int l   = t & 63;
  const int l15 = l & 15;
  const int lhi = l >> 4;   // 0..3

  floatx4 acc[2][2];
#pragma unroll
  for (int ia = 0; ia < 2; ++ia) {
#pragma unroll
    for (int r = 0; r < 4; ++r) {
      float bias = b_d[g * 128 + wv * 32 + ia * 16 + lhi * 4 + r];
#pragma unroll
      for (int jb = 0; jb < 2; ++jb) acc[ia][jb][r] = bias;
    }
  }

  const int spos = t >> 3;  // staging: 32 pos x 8 c-slices of 16 shorts
  const int scq  = t & 7;
  const int swz  = (spos & 7) << 3;   // XOR swizzle for this row, in shorts
  const ushort* xb = xT + (size_t)(b * 3 + g) * SLAB;
  const ushort* wg = wB + (size_t)g * 9 * 16384;

  for (int k = 0; k < 9; ++k) {
    // --- stage bilinear samples (fp32 blend -> packed bf16) ----------------
    {
      int off   = off_s[k][spos];
      float4 w4 = w4_s[k][spos];
      const ushort* p00 = xb + off + scq * 16;  // corners: +0,+128,+8192,+8320
      const ushort* p10 = p00 + 8192;
#pragma unroll
      for (int j = 0; j < 2; ++j) {
        uintx4 a00 = *(const uintx4*)(p00 + j * 8);
        uintx4 a01 = *(const uintx4*)(p00 + j * 8 + 128);
        uintx4 a10 = *(const uintx4*)(p10 + j * 8);
        uintx4 a11 = *(const uintx4*)(p10 + j * 8 + 128);
        uintx4 pk;
#pragma unroll
        for (int d = 0; d < 4; ++d) {
          float lo = fmaf(bf_lo(a11[d]), w4.w, fmaf(bf_lo(a10[d]), w4.z,
                     fmaf(bf_lo(a01[d]), w4.y, bf_lo(a00[d]) * w4.x)));
          float hi = fmaf(bf_hi(a11[d]), w4.w, fmaf(bf_hi(a10[d]), w4.z,
                     fmaf(bf_hi(a01[d]), w4.y, bf_hi(a00[d]) * w4.x)));
          pk[d] = cvtpk_bf16(lo, hi);
        }
        *(uintx4*)&samp[spos][(scq * 16 + j * 8) ^ swz] = pk;
      }
    }
    __syncthreads();

    // --- MFMA: acc += W_frag x S_frag over K=128 (4 ksteps) ----------------
    const ushort* wk = wg + (size_t)k * 16384;
#pragma unroll
    for (int s = 0; s < 4; ++s) {
      short8 a0 = *(const short8*)(wk + ((s * 8 + wv * 2 + 0) * 64 + l) * 8);
      short8 a1 = *(const short8*)(wk + ((s * 8 + wv * 2 + 1) * 64 + l) * 8);
      const int cb = (s * 32 + lhi * 8) ^ ((l15 & 7) << 3);
#pragma unroll
      for (int jb = 0; jb < 2; ++jb) {
        short8 bf = *(const short8*)&samp[jb * 16 + l15][cb];
        acc[0][jb] = __builtin_amdgcn_mfma_f32_16x16x32_bf16(a0, bf, acc[0][jb], 0, 0, 0);
        acc[1][jb] = __builtin_amdgcn_mfma_f32_16x16x32_bf16(a1, bf, acc[1][jb], 0, 0, 0);
      }
    }
    __syncthreads();  // samp reads done before next tap's writes
  }

  // --- store: out (B, 384, H, W); C col(lane&15) = pos = contiguous W -------
#pragma unroll
  for (int ia = 0; ia < 2; ++ia) {
#pragma unroll
    for (int jb = 0; jb < 2; ++jb) {
#pragma unroll
      for (int r = 0; r < 4; ++r) {
        int o = wv * 32 + ia * 16 + lhi * 4 + r;
        int pos = pos0 + jb * 16 + l15;
        out[(((size_t)(b * 384 + g * 128 + o)) * 64 + h) * 64 + pos] = acc[ia][jb][r];
      }
    }
  }
}

extern "C" void kernel_launch(void* const* d_in, const int* in_sizes, int n_in,
                              void* d_out, int out_size, void* d_ws, size_t ws_size,
                              hipStream_t stream) {
  const float* input   = (const float*)d_in[0];
  const float* wh_pred = (const float*)d_in[1];
  const float* w_off   = (const float*)d_in[2];
  const float* b_off   = (const float*)d_in[3];
  const float* w_d     = (const float*)d_in[4];
  const float* b_d     = (const float*)d_in[5];
  float* out = (float*)d_out;

  // layout: [head guard][24 slabs of xT][tail guard][wB]
  ushort* xT = (ushort*)d_ws + XT_GUARD;            // 24*SLAB shorts = 25.2 MB
  ushort* wB = xT + (size_t)24 * SLAB + XT_TAIL;    // 442368 bf16 = 0.88 MB

  transpose_x_kernel<<<dim3(8, 64, 24), 256, 0, stream>>>(input, xT);
  swizzle_w_kernel<<<dim3(1728), 256, 0, stream>>>(w_d, wB);
  fa_main_mfma<<<dim3(3072), 256, 0, stream>>>(
      xT, wB, wh_pred, w_off, b_off, b_d, out);
}